// Round 9
// baseline (82.569 us; speedup 1.0000x reference)
//
#include <hip/hip_runtime.h>

// out[n,m] = exp(i1[n]·i2[m] - ||i1[n]||^2/2 - ||i2[m]||^2/2), N=M=4096, D=32, f32.
// R8 verified: 3-pass hi/lo bf16 MFMA numerics OK (absmax 4.8e-7). dur 82.1 =
// ~57us harness fills + ~25us kernel (model says 13). R9: kill staging/barriers:
// pre-kernel converts A,B -> bf16 hi/lo + negated half-norms in d_ws; main
// kernel loads fragments DIRECTLY from global (L2-hot), zero LDS, zero barriers.

#define DD 32
#define BT 128

typedef __attribute__((ext_vector_type(8))) short bfrag8;
typedef __attribute__((ext_vector_type(4))) float f32x4;

__device__ __forceinline__ unsigned short f2bf_rn(float f) {
    unsigned u = __builtin_bit_cast(unsigned, f);
    u += 0x7FFFu + ((u >> 16) & 1u);      // RNE (inputs finite)
    return (unsigned short)(u >> 16);
}
__device__ __forceinline__ float bf2f(unsigned short h) {
    unsigned u = ((unsigned)h) << 16;
    return __builtin_bit_cast(float, u);
}

// ---- pre-kernel: one row per thread; f32 -> (hi,lo) bf16 + negated half-norm ----
__global__ __launch_bounds__(64) void rbf_pre_kernel(
    const float* __restrict__ A, const float* __restrict__ B,
    unsigned short* __restrict__ ah, unsigned short* __restrict__ al,
    unsigned short* __restrict__ bh, unsigned short* __restrict__ bl,
    float* __restrict__ nhA, float* __restrict__ nhB, int N)
{
    const int r   = blockIdx.x * 64 + threadIdx.x;   // 0 .. N+M-1
    const bool isB = r >= N;
    const int row = isB ? r - N : r;
    const float4* src = reinterpret_cast<const float4*>((isB ? B : A) + (size_t)row * DD);
    unsigned short* dh = (isB ? bh : ah) + (size_t)row * DD;
    unsigned short* dl = (isB ? bl : al) + (size_t)row * DD;
    float s = 0.f;
    #pragma unroll
    for (int q = 0; q < 8; ++q) {
        float4 v = src[q];
        s += v.x * v.x + v.y * v.y + v.z * v.z + v.w * v.w;
        ushort4 h, l;
        h.x = f2bf_rn(v.x); l.x = f2bf_rn(v.x - bf2f(h.x));
        h.y = f2bf_rn(v.y); l.y = f2bf_rn(v.y - bf2f(h.y));
        h.z = f2bf_rn(v.z); l.z = f2bf_rn(v.z - bf2f(h.z));
        h.w = f2bf_rn(v.w); l.w = f2bf_rn(v.w - bf2f(h.w));
        *reinterpret_cast<ushort4*>(dh + q * 4) = h;
        *reinterpret_cast<ushort4*>(dl + q * 4) = l;
    }
    ((isB ? nhB : nhA))[row] = -0.5f * s;
}

// ---- main: no LDS, no barriers; frags direct from global (L2-hot) ----
__global__ __launch_bounds__(256, 4) void rbf_mfma2_kernel(
    const unsigned short* __restrict__ ah, const unsigned short* __restrict__ al,
    const unsigned short* __restrict__ bh, const unsigned short* __restrict__ bl,
    const float* __restrict__ nhA, const float* __restrict__ nhB,
    float* __restrict__ out, int M)
{
    const int tid  = threadIdx.x;
    const int brow = blockIdx.y * BT;
    const int bcol = blockIdx.x * BT;
    const int lane = tid & 63, wid = tid >> 6;
    const int r0 = wid * 32;            // wave's 32-row strip
    const int lr = lane & 15;           // A row / B col / D col
    const int lg = lane >> 4;           // k-chunk; D row group
    const int k0 = lg * 8;

    const size_t arow = (size_t)(brow + r0 + lr) * DD + k0;
    const bfrag8 ah0 = *reinterpret_cast<const bfrag8*>(ah + arow);
    const bfrag8 al0 = *reinterpret_cast<const bfrag8*>(al + arow);
    const bfrag8 ah1 = *reinterpret_cast<const bfrag8*>(ah + arow + (size_t)16 * DD);
    const bfrag8 al1 = *reinterpret_cast<const bfrag8*>(al + arow + (size_t)16 * DD);

    float nha0[4], nha1[4];
    #pragma unroll
    for (int q = 0; q < 4; ++q) {
        nha0[q] = nhA[brow + r0 + lg * 4 + q];
        nha1[q] = nhA[brow + r0 + 16 + lg * 4 + q];
    }

    const size_t orow0 = (size_t)(brow + r0 + lg * 4) * M + bcol;

    #pragma unroll 2
    for (int c = 0; c < 8; ++c) {
        const int c0 = c * 16;
        const size_t brow_off = (size_t)(bcol + c0 + lr) * DD + k0;
        const bfrag8 bhf = *reinterpret_cast<const bfrag8*>(bh + brow_off);
        const bfrag8 blf = *reinterpret_cast<const bfrag8*>(bl + brow_off);
        const float nhb = nhB[bcol + c0 + lr];

        f32x4 acc0 = {0.f, 0.f, 0.f, 0.f}, acc1 = {0.f, 0.f, 0.f, 0.f};
        acc0 = __builtin_amdgcn_mfma_f32_16x16x32_bf16(al0, bhf, acc0, 0, 0, 0);
        acc1 = __builtin_amdgcn_mfma_f32_16x16x32_bf16(al1, bhf, acc1, 0, 0, 0);
        acc0 = __builtin_amdgcn_mfma_f32_16x16x32_bf16(ah0, blf, acc0, 0, 0, 0);
        acc1 = __builtin_amdgcn_mfma_f32_16x16x32_bf16(ah1, blf, acc1, 0, 0, 0);
        acc0 = __builtin_amdgcn_mfma_f32_16x16x32_bf16(ah0, bhf, acc0, 0, 0, 0);
        acc1 = __builtin_amdgcn_mfma_f32_16x16x32_bf16(ah1, bhf, acc1, 0, 0, 0);

        float* p0 = out + orow0 + c0 + lr;   // D: col=lane&15, row=lg*4+q (m89-verified)
        #pragma unroll
        for (int q = 0; q < 4; ++q) {
            p0[(size_t)q * M]        = __expf(acc0[q] + nha0[q] + nhb);
            p0[(size_t)(q + 16) * M] = __expf(acc1[q] + nha1[q] + nhb);
        }
    }
}

extern "C" void kernel_launch(void* const* d_in, const int* in_sizes, int n_in,
                              void* d_out, int out_size, void* d_ws, size_t ws_size,
                              hipStream_t stream) {
    const float* A = (const float*)d_in[0];
    const float* B = (const float*)d_in[1];
    float* out     = (float*)d_out;
    const int N = in_sizes[0] / DD;   // 4096
    const int M = in_sizes[1] / DD;   // 4096

    char* ws = (char*)d_ws;
    unsigned short* ah = (unsigned short*)(ws);
    unsigned short* al = (unsigned short*)(ws + 0x40000);
    unsigned short* bh = (unsigned short*)(ws + 0x80000);
    unsigned short* bl = (unsigned short*)(ws + 0xC0000);
    float* nhA = (float*)(ws + 0x100000);
    float* nhB = (float*)(ws + 0x104000);

    rbf_pre_kernel<<<(N + M) / 64, 64, 0, stream>>>(A, B, ah, al, bh, bl, nhA, nhB, N);
    dim3 grid(M / BT, N / BT);        // 32 x 32 = 1024 blocks
    rbf_mfma2_kernel<<<grid, 256, 0, stream>>>(ah, al, bh, bl, nhA, nhB, out, M);
}